// Round 1
// baseline (467.270 us; speedup 1.0000x reference)
//
#include <hip/hip_runtime.h>
#include <stdint.h>

#define BDIM 32
#define CDIM 32
#define LDIM 1024
#define VDIM 4096
#define BCL (BDIM*CDIM*LDIM)

// ---------------------------------------------------------------- init
__global__ void init_kernel(const float* __restrict__ f, const float* __restrict__ emb,
                            float* __restrict__ f_rest, float* __restrict__ f_hat,
                            float* __restrict__ e_sq, float* __restrict__ loss_acc) {
    int i = blockIdx.x * blockDim.x + threadIdx.x;
    if (i < BCL) { f_rest[i] = f[i]; f_hat[i] = 0.0f; }
    if (i < VDIM) {
        const float4* e4 = (const float4*)(emb + (size_t)i * CDIM);
        float s = 0.f;
#pragma unroll
        for (int k = 0; k < 8; ++k) {
            float4 v = e4[k];
            s += v.x*v.x; s += v.y*v.y; s += v.z*v.z; s += v.w*v.w;
        }
        e_sq[i] = s;
    }
    if (i == 0) *loss_acc = 0.f;
}

// ---------------------------------------------------------------- VQ argmin
__device__ __forceinline__ void load_z(const float* __restrict__ f_rest, int q, int pl, int s,
                                       float* z, float& zz) {
    int b = q / pl;
    int j = q - b * pl;
    zz = 0.f;
    if (pl == LDIM) {
        const float* base = f_rest + b * (CDIM * LDIM) + j;
#pragma unroll
        for (int c = 0; c < 32; ++c) { float v = base[c * LDIM]; z[c] = v; zz = fmaf(v, v, zz); }
    } else {
        int col = j * s + (s >> 1) - 1;
        const float* base = f_rest + b * (CDIM * LDIM) + col;
#pragma unroll
        for (int c = 0; c < 32; ++c) {
            float v = 0.5f * (base[c * LDIM] + base[c * LDIM + 1]);
            z[c] = v; zz = fmaf(v, v, zz);
        }
    }
}

__global__ __launch_bounds__(256) void vq_kernel(
    const float* __restrict__ f_rest, const float* __restrict__ emb,
    const float* __restrict__ e_sq, unsigned long long* __restrict__ keys,
    int pl, int s, int NQ, int vchunks)
{
    const int t = threadIdx.x;
    const int qg = blockIdx.x / vchunks;
    const int vc = blockIdx.x % vchunks;
    const int VC = VDIM / vchunks;
    const int tiles = VC >> 6;

    const int ql = t & 31;
    const int vslot = t >> 5;

    int q0 = (qg << 6) + ql;
    int q1 = q0 + 32;
    int qc0 = (q0 < NQ) ? q0 : NQ - 1;
    int qc1 = (q1 < NQ) ? q1 : NQ - 1;

    float z0[32], z1[32];
    float zz0, zz1;
    load_z(f_rest, qc0, pl, s, z0, zz0);
    load_z(f_rest, qc1, pl, s, z1, zz1);

    __shared__ float4 emb_s4[64 * 8];
    __shared__ float  esq_s[64];
    __shared__ float  red_d[256];
    __shared__ int    red_v[256];

    float best_d0 = 3.4e38f, best_d1 = 3.4e38f;
    int best_v0 = 0, best_v1 = 0;

    const int vbase0 = vc * VC;
    for (int tile = 0; tile < tiles; ++tile) {
        int vbase = vbase0 + (tile << 6);
        const float4* g4 = (const float4*)emb + (size_t)vbase * 8;
        emb_s4[2 * t]     = g4[2 * t];
        emb_s4[2 * t + 1] = g4[2 * t + 1];
        if (t < 64) esq_s[t] = e_sq[vbase + t];
        __syncthreads();
#pragma unroll
        for (int k = 0; k < 8; ++k) {
            int row = (vslot << 3) + k;
            float dot0 = 0.f, dot1 = 0.f;
#pragma unroll
            for (int c4 = 0; c4 < 8; ++c4) {
                float4 e = emb_s4[row * 8 + c4];
                dot0 = fmaf(z0[c4*4+0], e.x, dot0);
                dot0 = fmaf(z0[c4*4+1], e.y, dot0);
                dot0 = fmaf(z0[c4*4+2], e.z, dot0);
                dot0 = fmaf(z0[c4*4+3], e.w, dot0);
                dot1 = fmaf(z1[c4*4+0], e.x, dot1);
                dot1 = fmaf(z1[c4*4+1], e.y, dot1);
                dot1 = fmaf(z1[c4*4+2], e.z, dot1);
                dot1 = fmaf(z1[c4*4+3], e.w, dot1);
            }
            float d0 = (zz0 + esq_s[row]) - 2.0f * dot0;
            float d1 = (zz1 + esq_s[row]) - 2.0f * dot1;
            int v = vbase + row;
            if (d0 < best_d0) { best_d0 = d0; best_v0 = v; }
            if (d1 < best_d1) { best_d1 = d1; best_v1 = v; }
        }
        __syncthreads();
    }

    // reduce across the 8 vslots for each query; pack (d,idx) so u64 min == (min d, then min idx)
    red_d[t] = best_d0; red_v[t] = best_v0;
    __syncthreads();
    if (t < 32) {
        float bd = red_d[t]; int bv = red_v[t];
#pragma unroll
        for (int m = 1; m < 8; ++m) {
            float d = red_d[m * 32 + t]; int v = red_v[m * 32 + t];
            if (d < bd || (d == bd && v < bv)) { bd = d; bv = v; }
        }
        int q = (qg << 6) + t;
        if (q < NQ) {
            unsigned long long key = ((unsigned long long)__float_as_uint(bd) << 32) | (unsigned int)bv;
            atomicMin(&keys[q], key);
        }
    }
    __syncthreads();
    red_d[t] = best_d1; red_v[t] = best_v1;
    __syncthreads();
    if (t < 32) {
        float bd = red_d[t]; int bv = red_v[t];
#pragma unroll
        for (int m = 1; m < 8; ++m) {
            float d = red_d[m * 32 + t]; int v = red_v[m * 32 + t];
            if (d < bd || (d == bd && v < bv)) { bd = d; bv = v; }
        }
        int q = (qg << 6) + 32 + t;
        if (q < NQ) {
            unsigned long long key = ((unsigned long long)__float_as_uint(bd) << 32) | (unsigned int)bv;
            atomicMin(&keys[q], key);
        }
    }
}

// ---------------------------------------------------------------- fused gather+upsample+phi+update+loss
__global__ __launch_bounds__(256) void fuse_kernel(
    const float* __restrict__ f, const float* __restrict__ emb,
    const unsigned long long* __restrict__ keys,
    const float* __restrict__ w, const float* __restrict__ bias,
    float* __restrict__ f_rest, float* __restrict__ f_hat,
    float* __restrict__ loss_acc, int pl)
{
    const int t  = threadIdx.x;
    const int b  = blockIdx.y;
    const int l0 = blockIdx.x * 128;

    __shared__ float w_s[3072];      // [o][i][k]
    __shared__ float b_s[32];
    __shared__ float hs[32 * 132];   // [i][130 (+pad)] : col x -> l = l0 - 1 + x
    __shared__ float red[4];

    for (int x = t; x < 3072; x += 256) w_s[x] = w[x];
    if (t < 32) b_s[t] = bias[t];

    if (t < 130) {
        int l = l0 - 1 + t;
        if (l < 0 || l >= LDIM) {
#pragma unroll
            for (int i = 0; i < 32; ++i) hs[i * 132 + t] = 0.f;
        } else {
            int lo, hi; float wg;
            if (pl == LDIM) { lo = l; hi = l; wg = 0.f; }
            else {
                float pos = (l + 0.5f) * ((float)pl / 1024.0f) - 0.5f;
                pos = fminf(fmaxf(pos, 0.f), (float)(pl - 1));
                lo = (int)floorf(pos);
                hi = min(lo + 1, pl - 1);
                wg = pos - (float)lo;
            }
            int v0 = (int)(keys[b * pl + lo] & 0xFFFFFFFFull);
            int v1 = (int)(keys[b * pl + hi] & 0xFFFFFFFFull);
            const float4* e0 = (const float4*)(emb + (size_t)v0 * 32);
            const float4* e1 = (const float4*)(emb + (size_t)v1 * 32);
            float om = 1.0f - wg;
#pragma unroll
            for (int i4 = 0; i4 < 8; ++i4) {
                float4 a = e0[i4]; float4 c = e1[i4];
                hs[(i4*4+0) * 132 + t] = a.x * om + c.x * wg;
                hs[(i4*4+1) * 132 + t] = a.y * om + c.y * wg;
                hs[(i4*4+2) * 132 + t] = a.z * om + c.z * wg;
                hs[(i4*4+3) * 132 + t] = a.w * om + c.w * wg;
            }
        }
    }
    __syncthreads();

    const int o  = t >> 3;        // output channel, fixed per thread (w reuse x16)
    const int lg = t & 7;         // 16 consecutive l's per thread
    const float* wrow = &w_s[o * 96];
    float acc[16];
#pragma unroll
    for (int u = 0; u < 16; ++u) acc[u] = 0.f;
    const int hbase = lg * 16;    // hs col for l = l0 + lg*16 - 1

    for (int i = 0; i < 32; ++i) {
        float w0 = wrow[i * 3 + 0], w1 = wrow[i * 3 + 1], w2 = wrow[i * 3 + 2];
        const float* hrow = &hs[i * 132 + hbase];
        float hw[18];
#pragma unroll
        for (int x = 0; x < 18; ++x) hw[x] = hrow[x];
#pragma unroll
        for (int u = 0; u < 16; ++u) {
            acc[u] = fmaf(w0, hw[u], acc[u]);
            acc[u] = fmaf(w1, hw[u + 1], acc[u]);
            acc[u] = fmaf(w2, hw[u + 2], acc[u]);
        }
    }

    float lsum = 0.f;
    const int gbase = (b * 32 + o) * LDIM + l0 + lg * 16;
#pragma unroll
    for (int u = 0; u < 16; ++u) {
        float hval = hs[o * 132 + lg * 16 + 1 + u];
        float y = acc[u] + b_s[o];
        float ph = 0.5f * hval + 0.5f * y;    // h*(1-RESI) + (conv+b)*RESI, RESI=0.5
        int gi = gbase + u;
        float fh = f_hat[gi] + ph;
        f_hat[gi] = fh;
        f_rest[gi] -= ph;
        float df = fh - f[gi];
        lsum = fmaf(df, df, lsum);
    }

#pragma unroll
    for (int off = 32; off > 0; off >>= 1) lsum += __shfl_down(lsum, off, 64);
    if ((t & 63) == 0) red[t >> 6] = lsum;
    __syncthreads();
    if (t == 0) atomicAdd(loss_acc, red[0] + red[1] + red[2] + red[3]);
}

// ---------------------------------------------------------------- loss finalize
__global__ void final_kernel(const float* __restrict__ loss_acc, float* __restrict__ out_loss) {
    // per scale: (BETA + 1) * sse/BCL ; summed over 6 scales then /6
    *out_loss = (*loss_acc) * (1.25f / (6.0f * (float)BCL));
}

// ---------------------------------------------------------------- launch
extern "C" void kernel_launch(void* const* d_in, const int* in_sizes, int n_in,
                              void* d_out, int out_size, void* d_ws, size_t ws_size,
                              hipStream_t stream)
{
    const float* f    = (const float*)d_in[0];
    const float* emb  = (const float*)d_in[1];
    const float* phiw = (const float*)d_in[2];
    const float* phib = (const float*)d_in[3];

    float* f_hat    = (float*)d_out;        // BCL floats
    float* out_loss = f_hat + BCL;          // +1 float

    char* ws = (char*)d_ws;
    float* f_rest               = (float*)ws;                                   // 4 MB
    unsigned long long* keys    = (unsigned long long*)(ws + (size_t)BCL * 4);  // 256 KB
    float* e_sq                 = (float*)(ws + (size_t)BCL * 4 + 32768 * 8);   // 16 KB
    float* loss_acc             = e_sq + VDIM;

    init_kernel<<<dim3((BCL + 255) / 256), 256, 0, stream>>>(f, emb, f_rest, f_hat, e_sq, loss_acc);

    const int pls[6]  = {1, 4, 16, 64, 256, 1024};
    const int vch[6]  = {64, 32, 16, 8, 4, 2};   // V-splits: parallelism for small scales
    const int pidx[6] = {0, 0, 1, 2, 3, 3};      // PhiPartiallyShared static tick lookup

    for (int si = 0; si < 6; ++si) {
        int pl = pls[si];
        int s  = LDIM / pl;
        int NQ = BDIM * pl;
        hipMemsetAsync(keys, 0xFF, (size_t)NQ * 8, stream);
        int qgroups = (NQ + 63) / 64;
        vq_kernel<<<dim3(qgroups * vch[si]), 256, 0, stream>>>(
            f_rest, emb, e_sq, keys, pl, s, NQ, vch[si]);
        fuse_kernel<<<dim3(8, 32), 256, 0, stream>>>(
            f, emb, keys, phiw + (size_t)pidx[si] * 3072, phib + (size_t)pidx[si] * 32,
            f_rest, f_hat, loss_acc, pl);
    }
    final_kernel<<<1, 1, 0, stream>>>(loss_acc, out_loss);
}